// Round 2
// baseline (140.495 us; speedup 1.0000x reference)
//
#include <hip/hip_runtime.h>
#include <hip/hip_bf16.h>

#define B_SZ 128
#define IN_CAPS 1152
#define N_CAPS 16
#define DIM 16

#define IPB 8                         // i's per pass-block
#define ICN (IN_CAPS / IPB)           // 144 partial slices
#define OUT_ELEMS (B_SZ * N_CAPS * DIM)   // 32768
#define HAT_CH  (16 * 16 * 16)        // shorts per chunk: [b][n][e]
#define HAT_BLK (IPB * HAT_CH)        // 32768 shorts per (ic,bt) block

typedef __attribute__((ext_vector_type(8))) short bf16x8;   // MFMA A/B frag
typedef __attribute__((ext_vector_type(4))) float f32x4;    // MFMA C/D frag

__device__ __forceinline__ unsigned short f2bf(float f) {   // RNE
    unsigned u = __float_as_uint(f);
    u = u + 0x7fffu + ((u >> 16) & 1u);
    return (unsigned short)(u >> 16);
}
__device__ __forceinline__ unsigned pk2(float lo, float hi) {
    return ((unsigned)f2bf(hi) << 16) | f2bf(lo);
}
__device__ __forceinline__ unsigned cvtpk(float lo, float hi) {   // HW packed cvt (RNE)
    union { __hip_bfloat162 h; unsigned u; } c;
    c.h = __float22bfloat162_rn(make_float2(lo, hi));
    return c.u;
}

// DPP sums (VALU pipe — no DS traffic)
__device__ __forceinline__ float dpp_sum16(float v) {
    v += __int_as_float(__builtin_amdgcn_update_dpp(0, __float_as_int(v), 0xB1, 0xF, 0xF, true));
    v += __int_as_float(__builtin_amdgcn_update_dpp(0, __float_as_int(v), 0x4E, 0xF, 0xF, true));
    v += __int_as_float(__builtin_amdgcn_update_dpp(0, __float_as_int(v), 0x124, 0xF, 0xF, true));
    v += __int_as_float(__builtin_amdgcn_update_dpp(0, __float_as_int(v), 0x128, 0xF, 0xF, true));
    return v;
}
__device__ __forceinline__ float dpp_sum8(float v) {
    v += __int_as_float(__builtin_amdgcn_update_dpp(0, __float_as_int(v), 0xB1, 0xF, 0xF, true));
    v += __int_as_float(__builtin_amdgcn_update_dpp(0, __float_as_int(v), 0x4E, 0xF, 0xF, true));
    v += __int_as_float(__builtin_amdgcn_update_dpp(0, __float_as_int(v), 0x141, 0xF, 0xF, true));
    return v;
}

// ---- pass 0 (fused prep + linear pass): reads f32 W,x directly (RNE cvt on
// the fly = bit-identical to the old conv_xw path). Per i: MFMA hat fragment;
// (a) store hat bf16 to workspace in CONSUMER layout hat[ic][bt][i][b][n][e],
// (b) accumulate the c=1/16 partial in f32 (softmax of zero logits is const).
// No LDS, no barriers. ----
__global__ __launch_bounds__(256)
void caps_pass0(const float* __restrict__ x, const float* __restrict__ W,
                unsigned short* __restrict__ hat, unsigned short* __restrict__ partial)
{
    const int tid  = threadIdx.x;
    const int lane = tid & 63;
    const int w    = tid >> 6;
    const int em   = lane & 15;       // D col = b (B operand = x)
    const int q    = lane >> 4;       // D rows = e = 4q+r
    const int bt   = blockIdx.x;      // 0..7
    const int ic   = blockIdx.y;      // 0..143
    const int i0   = ic * IPB;

    unsigned short* hp = hat + (size_t)(ic * 8 + bt) * HAT_BLK;

    f32x4 acc[4];
    #pragma unroll
    for (int np = 0; np < 4; ++np) acc[np] = (f32x4){0.f, 0.f, 0.f, 0.f};

    #pragma unroll
    for (int ch = 0; ch < IPB; ++ch) {
        const int i = i0 + ch;
        // B operand: x[b=em][i][0..7] -> bf16, k>=8 zeroed (kills A garbage)
        uint4 xu = {0u, 0u, 0u, 0u};
        if (q == 0) {
            const float4* xp = (const float4*)(x + ((size_t)(bt * 16 + em) * IN_CAPS + i) * 8);
            float4 a = xp[0], c = xp[1];
            xu.x = cvtpk(a.x, a.y); xu.y = cvtpk(a.z, a.w);
            xu.z = cvtpk(c.x, c.y); xu.w = cvtpk(c.z, c.w);
        }
        union { uint4 u; bf16x8 v; } bx; bx.u = xu;
        #pragma unroll
        for (int np = 0; np < 4; ++np) {
            const int nn = 4 * w + np;
            // A operand: W[nn][i][e=em][0..7] f32 -> bf16 (RNE, same as conv_xw)
            const float4* wp = (const float4*)(W + (((size_t)nn * IN_CAPS + i) * DIM + em) * 8);
            float4 wa = wp[0], wb2 = wp[1];
            union { uint4 u; bf16x8 v; } ax;
            ax.u.x = cvtpk(wa.x, wa.y);  ax.u.y = cvtpk(wa.z, wa.w);
            ax.u.z = cvtpk(wb2.x, wb2.y); ax.u.w = cvtpk(wb2.z, wb2.w);
            f32x4 cz = {0.f, 0.f, 0.f, 0.f};
            f32x4 d = __builtin_amdgcn_mfma_f32_16x16x32_bf16(ax.v, bx.v, cz, 0, 0, 0);
            acc[np][0] += d[0]; acc[np][1] += d[1];
            acc[np][2] += d[2]; acc[np][3] += d[3];
            // hat[ch][b=em][n=nn][e=4q..4q+3] bf16
            uint2 o = {cvtpk(d[0], d[1]), cvtpk(d[2], d[3])};
            *(uint2*)(hp + ch * HAT_CH + em * 256 + nn * 16 + 4 * q) = o;
        }
    }

    // partial[ic][b][n][e] pre-scaled by c = 1/16 (same layout as before)
    const int b_glb = bt * 16 + em;
    unsigned short* pp = partial + (((size_t)ic * B_SZ + b_glb) << 8);
    #pragma unroll
    for (int np = 0; np < 4; ++np) {
        const int nn = 4 * w + np;
        uint2 o = {cvtpk(acc[np][0] * 0.0625f, acc[np][1] * 0.0625f),
                   cvtpk(acc[np][2] * 0.0625f, acc[np][3] * 0.0625f)};
        *(uint2*)(pp + nn * 16 + 4 * q) = o;
    }
}

// ---- routing passes 1/2: pure consumers of materialized hat. No LDS, no
// barriers, no MFMA: prefetch all 8 chunks (16 uint4), softmax over n via
// 16-lane DPP rows, accumulate, write partial.
// MODE 1: pr = squash(accA+B).  MODE 2: pr = sq(accA+B)+sq(accB+B). ----
template<int MODE>
__global__ __launch_bounds__(256, 4)
void caps_pass_r(const unsigned short* __restrict__ hat, const float* __restrict__ Bb,
                 const float* __restrict__ accA, const float* __restrict__ accB,
                 unsigned short* __restrict__ partial)
{
    const int tid  = threadIdx.x;
    const int lane = tid & 63;
    const int w    = tid >> 6;
    const int n    = lane & 15;
    const int q    = lane >> 4;
    const int bt   = blockIdx.x;      // 0..7
    const int ic   = blockIdx.y;      // 0..143
    const int b_loc = 4 * w + q;
    const int b_glb = bt * 16 + b_loc;

    // ---- prologue: pr[e] for this thread's (b_glb, n) ----
    float pr[16];
    {
        const float4* bbp = (const float4*)(Bb + (n << 4));
        const float4* ap  = (const float4*)(accA + ((size_t)b_glb << 8) + (n << 4));
        float s[16], s2 = 0.f;
        #pragma unroll
        for (int k4 = 0; k4 < 4; ++k4) {
            float4 a = ap[k4], bb = bbp[k4];
            s[4*k4+0] = a.x + bb.x; s[4*k4+1] = a.y + bb.y;
            s[4*k4+2] = a.z + bb.z; s[4*k4+3] = a.w + bb.w;
        }
        #pragma unroll
        for (int e = 0; e < 16; ++e) s2 = fmaf(s[e], s[e], s2);
        float sc = sqrtf(s2) / (1.0f + s2);
        #pragma unroll
        for (int e = 0; e < 16; ++e) pr[e] = s[e] * sc;
        if (MODE == 2) {
            const float4* ap2 = (const float4*)(accB + ((size_t)b_glb << 8) + (n << 4));
            float t[16], t2 = 0.f;
            #pragma unroll
            for (int k4 = 0; k4 < 4; ++k4) {
                float4 a = ap2[k4], bb = bbp[k4];
                t[4*k4+0] = a.x + bb.x; t[4*k4+1] = a.y + bb.y;
                t[4*k4+2] = a.z + bb.z; t[4*k4+3] = a.w + bb.w;
            }
            #pragma unroll
            for (int e = 0; e < 16; ++e) t2 = fmaf(t[e], t[e], t2);
            float sc2 = sqrtf(t2) / (1.0f + t2);
            #pragma unroll
            for (int e = 0; e < 16; ++e) pr[e] = fmaf(t[e], sc2, pr[e]);
        }
    }

    // ---- prefetch this thread's full hat panel: 8 chunks x 32 B ----
    const unsigned short* hb = hat + (size_t)(ic * 8 + bt) * HAT_BLK + b_loc * 256 + n * 16;
    uint4 hu[16];
    #pragma unroll
    for (int ch = 0; ch < IPB; ++ch) {
        const uint4* rp = (const uint4*)(hb + (size_t)ch * HAT_CH);
        hu[2*ch]   = rp[0];
        hu[2*ch+1] = rp[1];
    }

    float acc[16];
    #pragma unroll
    for (int e = 0; e < 16; ++e) acc[e] = 0.f;

    #pragma unroll
    for (int ch = 0; ch < IPB; ++ch) {
        float h[16];
        {
            uint4 u0 = hu[2*ch], u1 = hu[2*ch+1];
            unsigned uu[8] = {u0.x, u0.y, u0.z, u0.w, u1.x, u1.y, u1.z, u1.w};
            #pragma unroll
            for (int j = 0; j < 8; ++j) {
                h[2*j]   = __uint_as_float(uu[j] << 16);
                h[2*j+1] = __uint_as_float(uu[j] & 0xFFFF0000u);
            }
        }
        float lg = 0.f;
        #pragma unroll
        for (int e = 0; e < 16; ++e) lg = fmaf(pr[e], h[e], lg);
        float p = __expf(lg);                 // |lg| small -> max-free (R7-R9 proven)
        float z = dpp_sum16(p);               // softmax over n = 16-lane DPP row
        float c = p * __builtin_amdgcn_rcpf(z);
        #pragma unroll
        for (int e = 0; e < 16; ++e) acc[e] = fmaf(c, h[e], acc[e]);
    }

    // ---- epilogue: bf16 partial[ic][b][n][e] (thread owns the row) ----
    unsigned short* pp = partial + (((size_t)ic * B_SZ + b_glb) << 8) + (n << 4);
    uint4 o0 = {pk2(acc[0], acc[1]),   pk2(acc[2], acc[3]),
                pk2(acc[4], acc[5]),   pk2(acc[6], acc[7])};
    uint4 o1 = {pk2(acc[8], acc[9]),   pk2(acc[10], acc[11]),
                pk2(acc[12], acc[13]), pk2(acc[14], acc[15])};
    *(uint4*)pp = o0;
    *(uint4*)(pp + 8) = o1;
}

// ---- reduce 144 bf16 slices. Grouped: 256 blocks x 256 thr; thread (grp=tid>>6)
// sums 36 slices at uint pos (2 els); LDS combine; FINAL adds B + squash (8-lane DPP). ----
template<bool FINAL>
__global__ __launch_bounds__(256)
void caps_reduce(const unsigned* __restrict__ partial, const float* __restrict__ Bb,
                 float2* __restrict__ acc, float2* __restrict__ out)
{
    const int tid = threadIdx.x;
    const int ps  = tid & 63;
    const int grp = tid >> 6;
    const int pos = blockIdx.x * 64 + ps;        // uint index in [0, 16384)

    float t0 = 0.f, t1 = 0.f;
    #pragma unroll 6
    for (int k = 0; k < ICN / 4; ++k) {
        unsigned u = partial[(size_t)(grp * (ICN / 4) + k) * (OUT_ELEMS / 2) + pos];
        t0 += __uint_as_float(u << 16);
        t1 += __uint_as_float(u & 0xFFFF0000u);
    }
    __shared__ float2 red[4][64];
    red[grp][ps] = make_float2(t0, t1);
    __syncthreads();

    if (tid < 64) {
        float2 a = red[0][ps], b = red[1][ps], c = red[2][ps], d = red[3][ps];
        float v0 = a.x + b.x + c.x + d.x;
        float v1 = a.y + b.y + c.y + d.y;
        if (!FINAL) {
            acc[pos] = make_float2(v0, v1);
        } else {
            const int n = (pos >> 3) & 15, ep = pos & 7;
            float2 bb = *(const float2*)(Bb + n * 16 + 2 * ep);
            v0 += bb.x; v1 += bb.y;
            float s2 = dpp_sum8(v0 * v0 + v1 * v1);   // e-row = 8 consecutive lanes
            float sc = sqrtf(s2) / (1.0f + s2);
            out[pos] = make_float2(v0 * sc, v1 * sc);
        }
    }
}

extern "C" void kernel_launch(void* const* d_in, const int* in_sizes, int n_in,
                              void* d_out, int out_size, void* d_ws, size_t ws_size,
                              hipStream_t stream)
{
    const float* x  = (const float*)d_in[0];   // [128,1152,8]
    const float* W  = (const float*)d_in[1];   // [16,1152,16,8]
    const float* Bb = (const float*)d_in[2];   // [16,16]
    float2* out = (float2*)d_out;              // [128,16,16] fp32

    float* accA = (float*)d_ws;                                    // 128 KB
    float* accB = accA + OUT_ELEMS;                                // 128 KB
    unsigned short* partial = (unsigned short*)(accB + OUT_ELEMS); // 144 x 64 KB = 9.4 MB
    unsigned short* hat = partial + (size_t)ICN * OUT_ELEMS;       // 75.5 MB bf16

    dim3 pg(B_SZ / 16, ICN);   // 8 x 144 = 1152 blocks

    caps_pass0<<<pg, 256, 0, stream>>>(x, W, hat, partial);
    caps_reduce<false><<<256, 256, 0, stream>>>((const unsigned*)partial, Bb, (float2*)accA, nullptr);
    caps_pass_r<1><<<pg, 256, 0, stream>>>(hat, Bb, accA, nullptr, partial);
    caps_reduce<false><<<256, 256, 0, stream>>>((const unsigned*)partial, Bb, (float2*)accB, nullptr);
    caps_pass_r<2><<<pg, 256, 0, stream>>>(hat, Bb, accA, accB, partial);
    caps_reduce<true><<<256, 256, 0, stream>>>((const unsigned*)partial, Bb, nullptr, out);
}

// Round 3
// 132.741 us; speedup vs baseline: 1.0584x; 1.0584x over previous
//
#include <hip/hip_runtime.h>
#include <hip/hip_bf16.h>

#define B_SZ 128
#define IN_CAPS 1152
#define N_CAPS 16
#define DIM 16

#define IPB 8                         // i's per pass-block
#define ICN (IN_CAPS / IPB)           // 144 partial slices
#define OUT_ELEMS (B_SZ * N_CAPS * DIM)   // 32768
#define HAT_BLK (IPB * 16 * 16 * 16)  // 32768 shorts per (ic,bt) block = 8192 uint2

typedef __attribute__((ext_vector_type(8))) short bf16x8;   // MFMA A/B frag
typedef __attribute__((ext_vector_type(4))) float f32x4;    // MFMA C/D frag

__device__ __forceinline__ unsigned short f2bf(float f) {   // RNE
    unsigned u = __float_as_uint(f);
    u = u + 0x7fffu + ((u >> 16) & 1u);
    return (unsigned short)(u >> 16);
}
__device__ __forceinline__ unsigned pk2(float lo, float hi) {
    return ((unsigned)f2bf(hi) << 16) | f2bf(lo);
}
__device__ __forceinline__ unsigned cvtpk(float lo, float hi) {   // HW packed cvt (RNE)
    union { __hip_bfloat162 h; unsigned u; } c;
    c.h = __float22bfloat162_rn(make_float2(lo, hi));
    return c.u;
}

// DPP sums (VALU pipe — no DS traffic)
__device__ __forceinline__ float dpp_sum16(float v) {
    v += __int_as_float(__builtin_amdgcn_update_dpp(0, __float_as_int(v), 0xB1, 0xF, 0xF, true));
    v += __int_as_float(__builtin_amdgcn_update_dpp(0, __float_as_int(v), 0x4E, 0xF, 0xF, true));
    v += __int_as_float(__builtin_amdgcn_update_dpp(0, __float_as_int(v), 0x124, 0xF, 0xF, true));
    v += __int_as_float(__builtin_amdgcn_update_dpp(0, __float_as_int(v), 0x128, 0xF, 0xF, true));
    return v;
}
__device__ __forceinline__ float dpp_sum8(float v) {
    v += __int_as_float(__builtin_amdgcn_update_dpp(0, __float_as_int(v), 0xB1, 0xF, 0xF, true));
    v += __int_as_float(__builtin_amdgcn_update_dpp(0, __float_as_int(v), 0x4E, 0xF, 0xF, true));
    v += __int_as_float(__builtin_amdgcn_update_dpp(0, __float_as_int(v), 0x141, 0xF, 0xF, true));
    return v;
}

// XCD-aware block decode: id%8 = XCD (round-robin dispatch). All 8 bt-blocks
// of an ic share one XCD (same id mod 8, ids 8 apart) -> W-slice fetched once
// per XCD L2 instead of 8x across XCDs.
__device__ __forceinline__ void decode_blk(int id, int& ic, int& bt) {
    const int xcd = id & 7, j = id >> 3;   // j in [0,144)
    ic = xcd * 18 + (j >> 3);
    bt = j & 7;
}

// ---- pass 0 (fused prep + linear pass): reads f32 W,x directly (RNE cvt on
// the fly). Per i: MFMA hat fragment; (a) store hat bf16 in PRODUCER order
// hat[ic][bt][ch][w][lane][np] -> each lane stores 32 B contiguous (2x uint4),
// wave stores 2 KB contiguous; (b) accumulate the c=1/16 partial in f32 and
// write it in the same producer order (reducer<0> un-permutes). ----
__global__ __launch_bounds__(256)
void caps_pass0(const float* __restrict__ x, const float* __restrict__ W,
                unsigned short* __restrict__ hat, unsigned short* __restrict__ partial)
{
    const int tid  = threadIdx.x;
    const int lane = tid & 63;
    const int w    = tid >> 6;
    const int em   = lane & 15;       // D col = b (B operand = x)
    const int q    = lane >> 4;       // D rows = e = 4q+r
    int ic, bt; decode_blk(blockIdx.x, ic, bt);
    const int i0   = ic * IPB;

    uint2* hw = (uint2*)(hat + (size_t)(ic * 8 + bt) * HAT_BLK)
              + (size_t)w * 256 + lane * 4;          // + ch*1024 (+np)

    f32x4 acc[4];
    #pragma unroll
    for (int np = 0; np < 4; ++np) acc[np] = (f32x4){0.f, 0.f, 0.f, 0.f};

    #pragma unroll
    for (int ch = 0; ch < IPB; ++ch) {
        const int i = i0 + ch;
        // B operand: x[b=em][i][0..7] -> bf16, k>=8 zeroed (kills A garbage)
        uint4 xu = {0u, 0u, 0u, 0u};
        if (q == 0) {
            const float4* xp = (const float4*)(x + ((size_t)(bt * 16 + em) * IN_CAPS + i) * 8);
            float4 a = xp[0], c = xp[1];
            xu.x = cvtpk(a.x, a.y); xu.y = cvtpk(a.z, a.w);
            xu.z = cvtpk(c.x, c.y); xu.w = cvtpk(c.z, c.w);
        }
        union { uint4 u; bf16x8 v; } bx; bx.u = xu;
        uint2 o[4];
        #pragma unroll
        for (int np = 0; np < 4; ++np) {
            const int nn = 4 * w + np;
            // A operand: W[nn][i][e=em][0..7] f32 -> bf16 (RNE)
            const float4* wp = (const float4*)(W + (((size_t)nn * IN_CAPS + i) * DIM + em) * 8);
            float4 wa = wp[0], wb2 = wp[1];
            union { uint4 u; bf16x8 v; } ax;
            ax.u.x = cvtpk(wa.x, wa.y);   ax.u.y = cvtpk(wa.z, wa.w);
            ax.u.z = cvtpk(wb2.x, wb2.y); ax.u.w = cvtpk(wb2.z, wb2.w);
            f32x4 cz = {0.f, 0.f, 0.f, 0.f};
            f32x4 d = __builtin_amdgcn_mfma_f32_16x16x32_bf16(ax.v, bx.v, cz, 0, 0, 0);
            acc[np][0] += d[0]; acc[np][1] += d[1];
            acc[np][2] += d[2]; acc[np][3] += d[3];
            o[np] = (uint2){cvtpk(d[0], d[1]), cvtpk(d[2], d[3])};  // e 4q..4q+3
        }
        uint4 s0 = {o[0].x, o[0].y, o[1].x, o[1].y};
        uint4 s1 = {o[2].x, o[2].y, o[3].x, o[3].y};
        *(uint4*)(hw + (size_t)ch * 1024)     = s0;   // lane-contiguous 32 B
        *(uint4*)(hw + (size_t)ch * 1024 + 2) = s1;
    }

    // partial in PRODUCER order: uint2 idx = bt*1024 + w*256 + lane*4 + np
    uint2* pp = (uint2*)partial + (size_t)ic * 8192 + bt * 1024 + w * 256 + lane * 4;
    uint2 po[4];
    #pragma unroll
    for (int np = 0; np < 4; ++np)
        po[np] = (uint2){cvtpk(acc[np][0] * 0.0625f, acc[np][1] * 0.0625f),
                         cvtpk(acc[np][2] * 0.0625f, acc[np][3] * 0.0625f)};
    uint4 q0 = {po[0].x, po[0].y, po[1].x, po[1].y};
    uint4 q1 = {po[2].x, po[2].y, po[3].x, po[3].y};
    *(uint4*)pp       = q0;
    *(uint4*)(pp + 2) = q1;
}

// ---- routing passes 1/2: pure consumers of materialized hat. No LDS, no
// barriers, no MFMA. Per chunk: 4 uint2 reads (eq quads) that coalesce into
// full 128B segments; softmax over n via 16-lane DPP rows; write partial in
// consumer order [ic][b][n][e].
// MODE 1: pr = squash(accA+B).  MODE 2: pr = sq(accA+B)+sq(accB+B). ----
template<int MODE>
__global__ __launch_bounds__(256, 4)
void caps_pass_r(const unsigned short* __restrict__ hat, const float* __restrict__ Bb,
                 const float* __restrict__ accA, const float* __restrict__ accB,
                 unsigned short* __restrict__ partial)
{
    const int tid  = threadIdx.x;
    const int lane = tid & 63;
    const int w    = tid >> 6;
    const int n    = lane & 15;
    const int q    = lane >> 4;
    int ic, bt; decode_blk(blockIdx.x, ic, bt);
    const int b_loc = 4 * w + q;
    const int b_glb = bt * 16 + b_loc;

    // ---- prologue: pr[e] for this thread's (b_glb, n) ----
    float pr[16];
    {
        const float4* bbp = (const float4*)(Bb + (n << 4));
        const float4* ap  = (const float4*)(accA + ((size_t)b_glb << 8) + (n << 4));
        float s[16], s2 = 0.f;
        #pragma unroll
        for (int k4 = 0; k4 < 4; ++k4) {
            float4 a = ap[k4], bb = bbp[k4];
            s[4*k4+0] = a.x + bb.x; s[4*k4+1] = a.y + bb.y;
            s[4*k4+2] = a.z + bb.z; s[4*k4+3] = a.w + bb.w;
        }
        #pragma unroll
        for (int e = 0; e < 16; ++e) s2 = fmaf(s[e], s[e], s2);
        float sc = sqrtf(s2) / (1.0f + s2);
        #pragma unroll
        for (int e = 0; e < 16; ++e) pr[e] = s[e] * sc;
        if (MODE == 2) {
            const float4* ap2 = (const float4*)(accB + ((size_t)b_glb << 8) + (n << 4));
            float t[16], t2 = 0.f;
            #pragma unroll
            for (int k4 = 0; k4 < 4; ++k4) {
                float4 a = ap2[k4], bb = bbp[k4];
                t[4*k4+0] = a.x + bb.x; t[4*k4+1] = a.y + bb.y;
                t[4*k4+2] = a.z + bb.z; t[4*k4+3] = a.w + bb.w;
            }
            #pragma unroll
            for (int e = 0; e < 16; ++e) t2 = fmaf(t[e], t[e], t2);
            float sc2 = sqrtf(t2) / (1.0f + t2);
            #pragma unroll
            for (int e = 0; e < 16; ++e) pr[e] = fmaf(t[e], sc2, pr[e]);
        }
    }

    // ---- prefetch hat panel in producer order: idx2 = ch*1024 + (n>>2)*256
    //      + (eq*16 + b_loc)*4 + (n&3) ----
    const uint2* hq = (const uint2*)(hat + (size_t)(ic * 8 + bt) * HAT_BLK)
                    + (size_t)(n >> 2) * 256 + b_loc * 4 + (n & 3);
    uint2 hu[32];
    #pragma unroll
    for (int ch = 0; ch < IPB; ++ch)
        #pragma unroll
        for (int eq = 0; eq < 4; ++eq)
            hu[ch * 4 + eq] = hq[(size_t)ch * 1024 + eq * 64];

    float acc[16];
    #pragma unroll
    for (int e = 0; e < 16; ++e) acc[e] = 0.f;

    #pragma unroll
    for (int ch = 0; ch < IPB; ++ch) {
        float h[16];
        {
            unsigned uu[8];
            #pragma unroll
            for (int eq = 0; eq < 4; ++eq) {
                uu[2*eq]   = hu[ch * 4 + eq].x;
                uu[2*eq+1] = hu[ch * 4 + eq].y;
            }
            #pragma unroll
            for (int j = 0; j < 8; ++j) {
                h[2*j]   = __uint_as_float(uu[j] << 16);
                h[2*j+1] = __uint_as_float(uu[j] & 0xFFFF0000u);
            }
        }
        float lg = 0.f;
        #pragma unroll
        for (int e = 0; e < 16; ++e) lg = fmaf(pr[e], h[e], lg);
        float p = __expf(lg);                 // |lg| small -> max-free (R7-R9 proven)
        float z = dpp_sum16(p);               // softmax over n = 16-lane DPP row
        float c = p * __builtin_amdgcn_rcpf(z);
        #pragma unroll
        for (int e = 0; e < 16; ++e) acc[e] = fmaf(c, h[e], acc[e]);
    }

    // ---- epilogue: bf16 partial[ic][b][n][e] (consumer order) ----
    unsigned short* pp = partial + (((size_t)ic * B_SZ + b_glb) << 8) + (n << 4);
    uint4 o0 = {pk2(acc[0], acc[1]),   pk2(acc[2], acc[3]),
                pk2(acc[4], acc[5]),   pk2(acc[6], acc[7])};
    uint4 o1 = {pk2(acc[8], acc[9]),   pk2(acc[10], acc[11]),
                pk2(acc[12], acc[13]), pk2(acc[14], acc[15])};
    *(uint4*)pp = o0;
    *(uint4*)(pp + 8) = o1;
}

// ---- reduce 144 bf16 slices. MODE 0: partial is in PRODUCER order (pass0) ->
// un-permute when writing acc[b][n][e]. MODE 1: identity acc write. MODE 2:
// FINAL adds B + squash (8-lane DPP; partial is consumer order). ----
template<int MODE>
__global__ __launch_bounds__(256)
void caps_reduce(const unsigned* __restrict__ partial, const float* __restrict__ Bb,
                 float2* __restrict__ acc, float2* __restrict__ out)
{
    const int tid = threadIdx.x;
    const int ps  = tid & 63;
    const int grp = tid >> 6;
    const int pos = blockIdx.x * 64 + ps;        // uint index in [0, 16384)

    float t0 = 0.f, t1 = 0.f;
    #pragma unroll 6
    for (int k = 0; k < ICN / 4; ++k) {
        unsigned u = partial[(size_t)(grp * (ICN / 4) + k) * (OUT_ELEMS / 2) + pos];
        t0 += __uint_as_float(u << 16);
        t1 += __uint_as_float(u & 0xFFFF0000u);
    }
    __shared__ float2 red[4][64];
    red[grp][ps] = make_float2(t0, t1);
    __syncthreads();

    if (tid < 64) {
        float2 a = red[0][ps], b = red[1][ps], c = red[2][ps], d = red[3][ps];
        float v0 = a.x + b.x + c.x + d.x;
        float v1 = a.y + b.y + c.y + d.y;
        if (MODE == 0) {
            // producer order: pos = bt*2048 + w*512 + q*128 + em*8 + np*2 + rp
            const int rp = pos & 1, np = (pos >> 1) & 3, em = (pos >> 3) & 15;
            const int qq = (pos >> 7) & 3, ww = (pos >> 9) & 3, btb = pos >> 11;
            const int bb_ = btb * 16 + em, nn = 4 * ww + np, ep = 2 * qq + rp;
            acc[(size_t)bb_ * 128 + nn * 8 + ep] = make_float2(v0, v1);
        } else if (MODE == 1) {
            acc[pos] = make_float2(v0, v1);
        } else {
            const int n = (pos >> 3) & 15, ep = pos & 7;
            float2 bb = *(const float2*)(Bb + n * 16 + 2 * ep);
            v0 += bb.x; v1 += bb.y;
            float s2 = dpp_sum8(v0 * v0 + v1 * v1);   // e-row = 8 consecutive lanes
            float sc = sqrtf(s2) / (1.0f + s2);
            out[pos] = make_float2(v0 * sc, v1 * sc);
        }
    }
}

extern "C" void kernel_launch(void* const* d_in, const int* in_sizes, int n_in,
                              void* d_out, int out_size, void* d_ws, size_t ws_size,
                              hipStream_t stream)
{
    const float* x  = (const float*)d_in[0];   // [128,1152,8]
    const float* W  = (const float*)d_in[1];   // [16,1152,16,8]
    const float* Bb = (const float*)d_in[2];   // [16,16]
    float2* out = (float2*)d_out;              // [128,16,16] fp32

    float* accA = (float*)d_ws;                                    // 128 KB
    float* accB = accA + OUT_ELEMS;                                // 128 KB
    unsigned short* partial = (unsigned short*)(accB + OUT_ELEMS); // 144 x 64 KB = 9.4 MB
    unsigned short* hat = partial + (size_t)ICN * OUT_ELEMS;       // 75.5 MB bf16

    caps_pass0<<<1152, 256, 0, stream>>>(x, W, hat, partial);
    caps_reduce<0><<<256, 256, 0, stream>>>((const unsigned*)partial, Bb, (float2*)accA, nullptr);
    caps_pass_r<1><<<1152, 256, 0, stream>>>(hat, Bb, accA, nullptr, partial);
    caps_reduce<1><<<256, 256, 0, stream>>>((const unsigned*)partial, Bb, (float2*)accB, nullptr);
    caps_pass_r<2><<<1152, 256, 0, stream>>>(hat, Bb, accA, accB, partial);
    caps_reduce<2><<<256, 256, 0, stream>>>((const unsigned*)partial, Bb, nullptr, out);
}